// Round 3
// baseline (273.273 us; speedup 1.0000x reference)
//
#include <hip/hip_runtime.h>
#include <math.h>

// Problem constants (fixed by the reference).
#define TOK   16
#define TOPA  2
#define NPAIR (TOK * TOPA)   // 32
#define DIM   1024
#define INTER 2816
#define NEXP  8

// Build a uniform 32-bit mask of pairs routed to expert e.
__device__ __forceinline__ unsigned pair_mask(const int* __restrict__ eidx, int e) {
    unsigned mask = 0;
    #pragma unroll
    for (int k = 0; k < NPAIR / 4; ++k) {
        const int4 v = ((const int4*)eidx)[k];
        mask |= (unsigned)(v.x == e) << (4 * k + 0);
        mask |= (unsigned)(v.y == e) << (4 * k + 1);
        mask |= (unsigned)(v.z == e) << (4 * k + 2);
        mask |= (unsigned)(v.w == e) << (4 * k + 3);
    }
    return mask;
}

__device__ __forceinline__ float dot4(float4 a, float4 b) {
    return a.x * b.x + a.y * b.y + a.z * b.z + a.w * b.w;
}

// ---------------------------------------------------------------------------
// Kernel 1: h[p][o] = silu(x[t].w1[e][o]) * (x[t].w3[e][o])
// Layout: 8 lanes per row. lane -> row r = base + (lane>>3), segment
// oct = lane&7 owns cols [oct*128, oct*128+128) = 32 float4.
// Wave = 8 rows; block (4 waves) = 32 rows; grid (INTER/32, NEXP).
// Pairs processed 4 at a time as k-loop accumulators; x re-read from L1.
// Weight loads flow continuously through the whole k-loop (no burst+stall).
// ---------------------------------------------------------------------------
__global__ __launch_bounds__(256) void moe_gate_up(
    const float* __restrict__ x,     // [TOK][DIM]
    const int*   __restrict__ eidx,  // [TOK][TOPA]
    const float* __restrict__ w1,    // [NEXP][INTER][DIM]
    const float* __restrict__ w3,    // [NEXP][INTER][DIM]
    float*       __restrict__ h)     // [NPAIR][INTER]
{
    const int e = blockIdx.y;
    unsigned mask = pair_mask(eidx, e);
    if (!mask) return;   // skip this expert's weights entirely

    const int tid  = threadIdx.x;
    const int lane = tid & 63;
    const int wave = tid >> 6;
    const int oct  = lane & 7;
    const int r    = blockIdx.x * 32 + wave * 8 + (lane >> 3);

    const float4* w1r = (const float4*)(w1 + ((size_t)e * INTER + r) * DIM) + oct * 32;
    const float4* w3r = (const float4*)(w3 + ((size_t)e * INTER + r) * DIM) + oct * 32;
    const float4* xb  = (const float4*)x + oct * 32;

    while (mask) {
        // Pull up to 4 pairs (pad with duplicates of p0; writes are guarded).
        int p0 = __builtin_ctz(mask); mask &= mask - 1;
        int p1 = p0, p2 = p0, p3 = p0, nv = 1;
        if (mask) { p1 = __builtin_ctz(mask); mask &= mask - 1; nv = 2;
        if (mask) { p2 = __builtin_ctz(mask); mask &= mask - 1; nv = 3;
        if (mask) { p3 = __builtin_ctz(mask); mask &= mask - 1; nv = 4; } } }

        const float4* x0 = xb + (size_t)(p0 >> 1) * (DIM / 4);
        const float4* x1 = xb + (size_t)(p1 >> 1) * (DIM / 4);
        const float4* x2 = xb + (size_t)(p2 >> 1) * (DIM / 4);
        const float4* x3 = xb + (size_t)(p3 >> 1) * (DIM / 4);

        float s10 = 0.f, s11 = 0.f, s12 = 0.f, s13 = 0.f;
        float s30 = 0.f, s31 = 0.f, s32 = 0.f, s33 = 0.f;

        #pragma unroll 4
        for (int k = 0; k < 32; ++k) {
            const float4 a  = w1r[k];
            const float4 b  = w3r[k];
            const float4 v0 = x0[k];
            const float4 v1 = x1[k];
            const float4 v2 = x2[k];
            const float4 v3 = x3[k];
            s10 += dot4(a, v0); s30 += dot4(b, v0);
            s11 += dot4(a, v1); s31 += dot4(b, v1);
            s12 += dot4(a, v2); s32 += dot4(b, v2);
            s13 += dot4(a, v3); s33 += dot4(b, v3);
        }

        // Reduce across the 8-lane segment group: 3 butterfly steps,
        // 8 independent chains -> fully pipelined.
        #pragma unroll
        for (int off = 1; off < 8; off <<= 1) {
            s10 += __shfl_xor(s10, off); s30 += __shfl_xor(s30, off);
            s11 += __shfl_xor(s11, off); s31 += __shfl_xor(s31, off);
            s12 += __shfl_xor(s12, off); s32 += __shfl_xor(s32, off);
            s13 += __shfl_xor(s13, off); s33 += __shfl_xor(s33, off);
        }

        // Lane oct==i writes pair i's output for this row.
        const float s1 = (oct == 0) ? s10 : (oct == 1) ? s11 : (oct == 2) ? s12 : s13;
        const float s3 = (oct == 0) ? s30 : (oct == 1) ? s31 : (oct == 2) ? s32 : s33;
        const int   ps = (oct == 0) ? p0  : (oct == 1) ? p1  : (oct == 2) ? p2  : p3;
        if (oct < nv) {
            const float g = s1 / (1.f + __expf(-s1));   // silu
            h[(size_t)ps * INTER + r] = g * s3;
        }
    }
}

// ---------------------------------------------------------------------------
// Kernel 2: out[p][d] = sum_o h[p][o] * w2[e][d][o]
// Layout: 16 lanes per row. lane -> row r = base + (lane>>4), segment
// hx = lane&15 owns cols [hx*176, hx*176+176) = 44 float4.
// Wave = 4 rows; block = 16 rows; grid (DIM/16, NEXP).
// ---------------------------------------------------------------------------
__global__ __launch_bounds__(256) void moe_down(
    const float* __restrict__ h,     // [NPAIR][INTER]
    const int*   __restrict__ eidx,  // [TOK][TOPA]
    const float* __restrict__ w2,    // [NEXP][DIM][INTER]
    float*       __restrict__ out)   // [NPAIR][DIM]
{
    const int e = blockIdx.y;
    unsigned mask = pair_mask(eidx, e);
    if (!mask) return;

    const int tid  = threadIdx.x;
    const int lane = tid & 63;
    const int wave = tid >> 6;
    const int hx   = lane & 15;
    const int r    = blockIdx.x * 16 + wave * 4 + (lane >> 4);

    const float4* w2r = (const float4*)(w2 + ((size_t)e * DIM + r) * INTER) + hx * 44;
    const float4* hb  = (const float4*)h + hx * 44;

    while (mask) {
        int p0 = __builtin_ctz(mask); mask &= mask - 1;
        int p1 = p0, p2 = p0, p3 = p0, nv = 1;
        if (mask) { p1 = __builtin_ctz(mask); mask &= mask - 1; nv = 2;
        if (mask) { p2 = __builtin_ctz(mask); mask &= mask - 1; nv = 3;
        if (mask) { p3 = __builtin_ctz(mask); mask &= mask - 1; nv = 4; } } }

        const float4* h0 = hb + (size_t)p0 * (INTER / 4);
        const float4* h1 = hb + (size_t)p1 * (INTER / 4);
        const float4* h2 = hb + (size_t)p2 * (INTER / 4);
        const float4* h3 = hb + (size_t)p3 * (INTER / 4);

        float s0 = 0.f, s1 = 0.f, s2 = 0.f, s3 = 0.f;

        #pragma unroll 4
        for (int k = 0; k < 44; ++k) {
            const float4 w = w2r[k];
            s0 += dot4(w, h0[k]);
            s1 += dot4(w, h1[k]);
            s2 += dot4(w, h2[k]);
            s3 += dot4(w, h3[k]);
        }

        // Reduce across the 16-lane segment group: 4 butterfly steps.
        #pragma unroll
        for (int off = 1; off < 16; off <<= 1) {
            s0 += __shfl_xor(s0, off);
            s1 += __shfl_xor(s1, off);
            s2 += __shfl_xor(s2, off);
            s3 += __shfl_xor(s3, off);
        }

        const float sv = (hx == 0) ? s0 : (hx == 1) ? s1 : (hx == 2) ? s2 : s3;
        const int   ps = (hx == 0) ? p0 : (hx == 1) ? p1 : (hx == 2) ? p2 : p3;
        if (hx < nv) {
            out[(size_t)ps * DIM + r] = sv;
        }
    }
}

// ---------------------------------------------------------------------------
extern "C" void kernel_launch(void* const* d_in, const int* in_sizes, int n_in,
                              void* d_out, int out_size, void* d_ws, size_t ws_size,
                              hipStream_t stream) {
    const float* x    = (const float*)d_in[0];
    const int*   eidx = (const int*)  d_in[1];
    const float* w1   = (const float*)d_in[2];
    const float* w2   = (const float*)d_in[3];
    const float* w3   = (const float*)d_in[4];
    float* out = (float*)d_out;
    float* hws = (float*)d_ws;   // [NPAIR][INTER] f32 = 360448 B

    dim3 g1(INTER / 32, NEXP);   // 88 x 8 blocks, 8 rows/wave
    moe_gate_up<<<g1, 256, 0, stream>>>(x, eidx, w1, w3, hws);

    dim3 g2(DIM / 16, NEXP);     // 64 x 8 blocks, 4 rows/wave
    moe_down<<<g2, 256, 0, stream>>>(hws, eidx, w2, out);
}

// Round 4
// 65.991 us; speedup vs baseline: 4.1411x; 4.1411x over previous
//
#include <hip/hip_runtime.h>
#include <math.h>

// Problem constants (fixed by the reference).
#define TOK   16
#define TOPA  2
#define NPAIR (TOK * TOPA)   // 32
#define DIM   1024
#define INTER 2816
#define NEXP  8

// Build a uniform 32-bit mask of pairs routed to expert e (ends up in SGPRs).
__device__ __forceinline__ unsigned pair_mask(const int* __restrict__ eidx, int e) {
    unsigned mask = 0;
    #pragma unroll
    for (int k = 0; k < NPAIR / 4; ++k) {
        const int4 v = ((const int4*)eidx)[k];
        mask |= (unsigned)(v.x == e) << (4 * k + 0);
        mask |= (unsigned)(v.y == e) << (4 * k + 1);
        mask |= (unsigned)(v.z == e) << (4 * k + 2);
        mask |= (unsigned)(v.w == e) << (4 * k + 3);
    }
    return mask;
}

__device__ __forceinline__ float dot4(float4 a, float4 b) {
    return a.x * b.x + a.y * b.y + a.z * b.z + a.w * b.w;
}

// ---------------------------------------------------------------------------
// Kernel 1: h[p][o] = silu(x[t].w1[e][o]) * (x[t].w3[e][o])
// Coalesced layout (R2-proven, FETCH ~= weights once): lane reads
// row[k*64+lane] float4 -> each wave instruction covers contiguous 1 KB.
// Wave owns 2 rows; block = 8 rows; grid (INTER/8, NEXP).
// Up to 4 pairs are k-loop accumulators sharing every weight load; one
// pipelined 16-chain butterfly per wave body.
// ---------------------------------------------------------------------------
__global__ __launch_bounds__(256) void moe_gate_up(
    const float* __restrict__ x,     // [TOK][DIM]
    const int*   __restrict__ eidx,  // [TOK][TOPA]
    const float* __restrict__ w1,    // [NEXP][INTER][DIM]
    const float* __restrict__ w3,    // [NEXP][INTER][DIM]
    float*       __restrict__ h)     // [NPAIR][INTER]
{
    const int e = blockIdx.y;
    unsigned mask = pair_mask(eidx, e);
    if (!mask) return;   // skip this expert's weights entirely

    const int tid  = threadIdx.x;
    const int lane = tid & 63;
    const int wave = tid >> 6;
    const int r0   = blockIdx.x * 8 + wave * 2;

    const float4* w1r = (const float4*)(w1 + ((size_t)e * INTER + r0) * DIM);
    const float4* w3r = (const float4*)(w3 + ((size_t)e * INTER + r0) * DIM);
    const float4* xb  = (const float4*)x;

    while (mask) {
        // Pull up to 4 pairs (pad with duplicates of p0; writes guarded by nv).
        int p0 = __builtin_ctz(mask); mask &= mask - 1;
        int p1 = p0, p2 = p0, p3 = p0, nv = 1;
        if (mask) { p1 = __builtin_ctz(mask); mask &= mask - 1; nv = 2;
        if (mask) { p2 = __builtin_ctz(mask); mask &= mask - 1; nv = 3;
        if (mask) { p3 = __builtin_ctz(mask); mask &= mask - 1; nv = 4; } } }

        const float4* x0 = xb + (size_t)(p0 >> 1) * (DIM / 4);
        const float4* x1 = xb + (size_t)(p1 >> 1) * (DIM / 4);
        const float4* x2 = xb + (size_t)(p2 >> 1) * (DIM / 4);
        const float4* x3 = xb + (size_t)(p3 >> 1) * (DIM / 4);

        float s1[2][4], s3[2][4];
        #pragma unroll
        for (int r = 0; r < 2; ++r)
            #pragma unroll
            for (int j = 0; j < 4; ++j) { s1[r][j] = 0.f; s3[r][j] = 0.f; }

        #pragma unroll
        for (int k = 0; k < 4; ++k) {
            const float4 a0 = w1r[k * 64 + lane];
            const float4 a1 = w1r[256 + k * 64 + lane];   // row r0+1
            const float4 b0 = w3r[k * 64 + lane];
            const float4 b1 = w3r[256 + k * 64 + lane];
            const float4 v0 = x0[k * 64 + lane];
            const float4 v1 = x1[k * 64 + lane];
            const float4 v2 = x2[k * 64 + lane];
            const float4 v3 = x3[k * 64 + lane];
            s1[0][0] += dot4(a0, v0); s1[0][1] += dot4(a0, v1);
            s1[0][2] += dot4(a0, v2); s1[0][3] += dot4(a0, v3);
            s1[1][0] += dot4(a1, v0); s1[1][1] += dot4(a1, v1);
            s1[1][2] += dot4(a1, v2); s1[1][3] += dot4(a1, v3);
            s3[0][0] += dot4(b0, v0); s3[0][1] += dot4(b0, v1);
            s3[0][2] += dot4(b0, v2); s3[0][3] += dot4(b0, v3);
            s3[1][0] += dot4(b1, v0); s3[1][1] += dot4(b1, v1);
            s3[1][2] += dot4(b1, v2); s3[1][3] += dot4(b1, v3);
        }

        // One pipelined butterfly: 16 independent chains x 6 levels.
        #pragma unroll
        for (int off = 1; off < 64; off <<= 1) {
            #pragma unroll
            for (int r = 0; r < 2; ++r)
                #pragma unroll
                for (int j = 0; j < 4; ++j) {
                    s1[r][j] += __shfl_xor(s1[r][j], off);
                    s3[r][j] += __shfl_xor(s3[r][j], off);
                }
        }

        if (lane == 0) {
            const int pp[4] = { p0, p1, p2, p3 };
            #pragma unroll
            for (int j = 0; j < 4; ++j) {
                if (j < nv) {
                    #pragma unroll
                    for (int r = 0; r < 2; ++r) {
                        const float g = s1[r][j] / (1.f + __expf(-s1[r][j]));
                        h[(size_t)pp[j] * INTER + r0 + r] = g * s3[r][j];
                    }
                }
            }
        }
    }
}

// ---------------------------------------------------------------------------
// Kernel 2: out[p][d] = sum_o h[p][o] * w2[e][d][o]
// Same structure: wave owns 2 rows of w2 (11 float4/lane each), up to 4
// pairs as accumulators, one 8-chain butterfly per wave body.
// grid (DIM/8, NEXP). h (360 KB) is L2-resident.
// ---------------------------------------------------------------------------
__global__ __launch_bounds__(256) void moe_down(
    const float* __restrict__ h,     // [NPAIR][INTER]
    const int*   __restrict__ eidx,  // [TOK][TOPA]
    const float* __restrict__ w2,    // [NEXP][DIM][INTER]
    float*       __restrict__ out)   // [NPAIR][DIM]
{
    const int e = blockIdx.y;
    unsigned mask = pair_mask(eidx, e);
    if (!mask) return;

    const int tid  = threadIdx.x;
    const int lane = tid & 63;
    const int wave = tid >> 6;
    const int r0   = blockIdx.x * 8 + wave * 2;

    const float4* w2r = (const float4*)(w2 + ((size_t)e * DIM + r0) * INTER);
    const float4* hb  = (const float4*)h;

    while (mask) {
        int p0 = __builtin_ctz(mask); mask &= mask - 1;
        int p1 = p0, p2 = p0, p3 = p0, nv = 1;
        if (mask) { p1 = __builtin_ctz(mask); mask &= mask - 1; nv = 2;
        if (mask) { p2 = __builtin_ctz(mask); mask &= mask - 1; nv = 3;
        if (mask) { p3 = __builtin_ctz(mask); mask &= mask - 1; nv = 4; } } }

        const float4* h0 = hb + (size_t)p0 * (INTER / 4);
        const float4* h1 = hb + (size_t)p1 * (INTER / 4);
        const float4* h2 = hb + (size_t)p2 * (INTER / 4);
        const float4* h3 = hb + (size_t)p3 * (INTER / 4);

        float s[2][4];
        #pragma unroll
        for (int r = 0; r < 2; ++r)
            #pragma unroll
            for (int j = 0; j < 4; ++j) s[r][j] = 0.f;

        #pragma unroll
        for (int k = 0; k < 11; ++k) {
            const float4 a0 = w2r[k * 64 + lane];
            const float4 a1 = w2r[704 + k * 64 + lane];   // row r0+1 (INTER/4 = 704)
            const float4 v0 = h0[k * 64 + lane];
            const float4 v1 = h1[k * 64 + lane];
            const float4 v2 = h2[k * 64 + lane];
            const float4 v3 = h3[k * 64 + lane];
            s[0][0] += dot4(a0, v0); s[0][1] += dot4(a0, v1);
            s[0][2] += dot4(a0, v2); s[0][3] += dot4(a0, v3);
            s[1][0] += dot4(a1, v0); s[1][1] += dot4(a1, v1);
            s[1][2] += dot4(a1, v2); s[1][3] += dot4(a1, v3);
        }

        // One pipelined butterfly: 8 independent chains x 6 levels.
        #pragma unroll
        for (int off = 1; off < 64; off <<= 1) {
            #pragma unroll
            for (int r = 0; r < 2; ++r)
                #pragma unroll
                for (int j = 0; j < 4; ++j)
                    s[r][j] += __shfl_xor(s[r][j], off);
        }

        if (lane == 0) {
            const int pp[4] = { p0, p1, p2, p3 };
            #pragma unroll
            for (int j = 0; j < 4; ++j) {
                if (j < nv) {
                    #pragma unroll
                    for (int r = 0; r < 2; ++r)
                        out[(size_t)pp[j] * DIM + r0 + r] = s[r][j];
                }
            }
        }
    }
}

// ---------------------------------------------------------------------------
extern "C" void kernel_launch(void* const* d_in, const int* in_sizes, int n_in,
                              void* d_out, int out_size, void* d_ws, size_t ws_size,
                              hipStream_t stream) {
    const float* x    = (const float*)d_in[0];
    const int*   eidx = (const int*)  d_in[1];
    const float* w1   = (const float*)d_in[2];
    const float* w2   = (const float*)d_in[3];
    const float* w3   = (const float*)d_in[4];
    float* out = (float*)d_out;
    float* hws = (float*)d_ws;   // [NPAIR][INTER] f32 = 360448 B

    dim3 g1(INTER / 8, NEXP);   // 352 x 8 blocks, 2 rows/wave
    moe_gate_up<<<g1, 256, 0, stream>>>(x, eidx, w1, w3, hws);

    dim3 g2(DIM / 8, NEXP);     // 128 x 8 blocks, 2 rows/wave
    moe_down<<<g2, 256, 0, stream>>>(hws, eidx, w2, out);
}